// Round 5
// baseline (153.186 us; speedup 1.0000x reference)
//
#include <hip/hip_runtime.h>
#include <hip/hip_bf16.h>
#include <math.h>

#define TAU_INV_LOG2E 14.4269504088896340736f  // (1/0.1) * log2(e)
#define EPS 1e-8f

typedef __attribute__((ext_vector_type(8))) short bf16x8;
typedef __attribute__((ext_vector_type(4))) float f32x4;

static __device__ __forceinline__ unsigned short f2bf(float f) {
    unsigned int u = __float_as_uint(f);
    unsigned int r = (u + 0x7fffu + ((u >> 16) & 1u)) >> 16;
    return (unsigned short)r;
}

// Kernel 1: L2-normalize rows of x (N x 256 fp32) -> xn (bf16). Zero out[0].
__global__ __launch_bounds__(256) void normalize_kernel(
    const float* __restrict__ x, unsigned short* __restrict__ xn,
    float* __restrict__ out, int N) {
    const int wave = threadIdx.x >> 6;
    const int lane = threadIdx.x & 63;
    const int row  = blockIdx.x * 4 + wave;
    if (row >= N) return;

    if (blockIdx.x == 0 && threadIdx.x == 0) out[0] = 0.0f;

    const float4 v = ((const float4*)(x + (size_t)row * 256))[lane];
    float s = v.x * v.x + v.y * v.y + v.z * v.z + v.w * v.w;
    s += __shfl_xor(s, 1);
    s += __shfl_xor(s, 2);
    s += __shfl_xor(s, 4);
    s += __shfl_xor(s, 8);
    s += __shfl_xor(s, 16);
    s += __shfl_xor(s, 32);
    const float norm = fmaxf(sqrtf(s), 1e-12f);
    const float rinv = 1.0f / norm;

    ushort4 o;
    o.x = f2bf(v.x * rinv);
    o.y = f2bf(v.y * rinv);
    o.z = f2bf(v.z * rinv);
    o.w = f2bf(v.w * rinv);
    ((ushort4*)(xn + (size_t)row * 256))[lane] = o;
}

// Kernel 2: strip GEMM. Each block = row-block bi x G=4 consecutive bj tiles
// (upper triangle). A-half (64x256) lives in 128 VGPRs per wave, loaded ONCE
// per block directly from global (xn is L2-resident). B fragments are loaded
// directly to registers per K-chunk. NO LDS, NO barriers, NO waitcnt games --
// waves fully independent; ILP (32 indep loads/tile) hides L2 latency.
// Row-sums accumulate in registers across the strip (one store per block);
// col-partials (symmetry) stored per off-diag tile.
// Slot ownership (atomic-free):
//   row-partials of strip (bi,sid) -> prowR[2*sid+waveN], rows bi*128..+127
//   col-partials of tile (bi,bj)   -> prowC[2*bi+waveM],  rows bj*128..+127
// Finalize for row-block a reads prowR slots [0, 2*ceil((B-a)/4)) and
// prowC slots [0, 2*a) -- exactly the written cells, each written once.
__global__ __launch_bounds__(256, 2) void gemm_strip_kernel(
    const unsigned short* __restrict__ xn, float* __restrict__ prowR,
    float* __restrict__ prowC, float* __restrict__ out, int N) {
    const int D = 256;
    const int tid   = threadIdx.x;
    const int wave  = tid >> 6;
    const int lane  = tid & 63;
    const int waveM = wave >> 1;
    const int waveN = wave & 1;
    const int quad  = lane >> 4;
    const int l16   = lane & 15;

    // decode strip: bi (row-block) and sid (strip index within the row)
    const int B = N >> 7;  // 64
    int rem = blockIdx.x, bi = 0;
    while (rem >= ((B - bi + 3) >> 2)) { rem -= (B - bi + 3) >> 2; ++bi; }
    const int sid   = rem;
    const int bj0   = bi + (sid << 2);
    const int bjEnd = min(bj0 + 3, B - 1);
    const int iBase = bi * 128;

    // A fragments: afr[kc][tt] holds A[iBase + waveM*64 + tt*16 + l16]
    //                              [kc*32 + quad*8 .. +7]   (16B per lane)
    // identical lane->element mapping to the verified LDS-read path.
    bf16x8 afr[8][4];
    {
        const unsigned short* aBase =
            xn + (size_t)(iBase + waveM * 64 + l16) * D + quad * 8;
        #pragma unroll
        for (int kc = 0; kc < 8; ++kc)
            #pragma unroll
            for (int tt = 0; tt < 4; ++tt)
                afr[kc][tt] = *(const bf16x8*)(aBase + (size_t)tt * 16 * D + kc * 32);
    }

    float rsum[4][4];
    #pragma unroll
    for (int mt = 0; mt < 4; ++mt)
        #pragma unroll
        for (int r = 0; r < 4; ++r) rsum[mt][r] = 0.f;

    for (int bj = bj0; bj <= bjEnd; ++bj) {
        const int jBase = bj * 128;
        const unsigned short* bBase =
            xn + (size_t)(jBase + waveN * 64 + l16) * D + quad * 8;

        f32x4 acc[4][4];
        #pragma unroll
        for (int mt = 0; mt < 4; ++mt)
            #pragma unroll
            for (int nt = 0; nt < 4; ++nt)
                acc[mt][nt] = (f32x4){0.f, 0.f, 0.f, 0.f};

        #pragma unroll
        for (int kc = 0; kc < 8; ++kc) {
            bf16x8 b[4];
            #pragma unroll
            for (int nt = 0; nt < 4; ++nt)
                b[nt] = *(const bf16x8*)(bBase + (size_t)nt * 16 * D + kc * 32);
            #pragma unroll
            for (int mt = 0; mt < 4; ++mt)
                #pragma unroll
                for (int nt = 0; nt < 4; ++nt)
                    acc[mt][nt] = __builtin_amdgcn_mfma_f32_16x16x32_bf16(
                        afr[kc][mt], b[nt], acc[mt][nt], 0, 0, 0);
        }

        // per-tile epilogue. C/D layout: col = l16, row = quad*4 + reg [m89]
        float csum[4] = {0.f, 0.f, 0.f, 0.f};
        #pragma unroll
        for (int mt = 0; mt < 4; ++mt) {
            const int gi0 = iBase + waveM * 64 + mt * 16 + quad * 4;
            #pragma unroll
            for (int nt = 0; nt < 4; ++nt) {
                const int gj = jBase + waveN * 64 + nt * 16 + l16;
                #pragma unroll
                for (int r = 0; r < 4; ++r) {
                    float e = __builtin_amdgcn_exp2f(acc[mt][nt][r] * TAU_INV_LOG2E);
                    if (gi0 + r == gj) e = 0.0f;  // diagonal (diag tile only)
                    rsum[mt][r] += e;
                    csum[nt] += e;
                }
            }
        }
        // col partials -> prowC slot 2*bi+waveM (off-diag tiles only)
        if (bj != bi) {
            float* slot = prowC + (size_t)(2 * bi + waveM) * N;
            #pragma unroll
            for (int nt = 0; nt < 4; ++nt) {
                float s = csum[nt];
                s += __shfl_xor(s, 16);
                s += __shfl_xor(s, 32);
                if (quad == 0)
                    slot[jBase + waveN * 64 + nt * 16 + l16] = s;
            }
        }
    }

    // row partials for the whole strip -> prowR slot 2*sid+waveN
    {
        float* slot = prowR + (size_t)(2 * sid + waveN) * N;
        #pragma unroll
        for (int mt = 0; mt < 4; ++mt) {
            const int gi0 = iBase + waveM * 64 + mt * 16 + quad * 4;
            #pragma unroll
            for (int r = 0; r < 4; ++r) {
                float s = rsum[mt][r];
                s += __shfl_xor(s, 1);
                s += __shfl_xor(s, 2);
                s += __shfl_xor(s, 4);
                s += __shfl_xor(s, 8);
                if (l16 == 0) slot[gi0 + r] = s;
            }
        }
    }
}

// Kernel 3: per row-block a, rowsum_i = sum of valid prowR/prowC slots;
// loss += log(rowsum/(N-1)+eps)/N. Grid = B blocks x 128 threads (1/row).
__global__ __launch_bounds__(128) void finalize_kernel(
    const float* __restrict__ prowR, const float* __restrict__ prowC,
    float* __restrict__ out, int N) {
    __shared__ float red[2];
    const int B = N >> 7;
    const int a = blockIdx.x;
    const int i = a * 128 + threadIdx.x;
    const int nR = 2 * ((B - a + 3) >> 2);  // valid row-partial slots
    const int nC = 2 * a;                   // valid col-partial slots
    float s = 0.f;
    for (int p = 0; p < nR; ++p) s += prowR[(size_t)p * N + i];
    for (int p = 0; p < nC; ++p) s += prowC[(size_t)p * N + i];
    float acc = logf(fmaf(s, 1.0f / (float)(N - 1), EPS));
    acc += __shfl_xor(acc, 1);
    acc += __shfl_xor(acc, 2);
    acc += __shfl_xor(acc, 4);
    acc += __shfl_xor(acc, 8);
    acc += __shfl_xor(acc, 16);
    acc += __shfl_xor(acc, 32);
    const int wave = threadIdx.x >> 6;
    const int lane = threadIdx.x & 63;
    if (lane == 0) red[wave] = acc;
    __syncthreads();
    if (threadIdx.x == 0) atomicAdd(out, (red[0] + red[1]) / (float)N);
}

extern "C" void kernel_launch(void* const* d_in, const int* in_sizes, int n_in,
                              void* d_out, int out_size, void* d_ws, size_t ws_size,
                              hipStream_t stream) {
    const float* x = (const float*)d_in[0];
    const int D = 256;
    const int N = in_sizes[0] / D;  // 8192
    const int B = N / 128;          // 64

    unsigned short* xn = (unsigned short*)d_ws;                 // 4 MB
    float* prowR = (float*)((char*)d_ws + (size_t)N * D * 2);   // 32 x N f32 = 1 MB
    float* prowC = prowR + (size_t)32 * N;                      // 128 x N f32 = 4 MB
    float* out = (float*)d_out;

    normalize_kernel<<<(N + 3) / 4, 256, 0, stream>>>(x, xn, out, N);

    int T = 0;
    for (int bi = 0; bi < B; ++bi) T += (B - bi + 3) >> 2;  // 544 strips
    gemm_strip_kernel<<<T, 256, 0, stream>>>(xn, prowR, prowC, out, N);

    finalize_kernel<<<B, 128, 0, stream>>>(prowR, prowC, out, N);
}

// Round 6
// 131.752 us; speedup vs baseline: 1.1627x; 1.1627x over previous
//
#include <hip/hip_runtime.h>
#include <hip/hip_bf16.h>
#include <math.h>

#define TAU_INV_LOG2E 14.4269504088896340736f  // (1/0.1) * log2(e)
#define EPS 1e-8f

typedef __attribute__((ext_vector_type(8))) short bf16x8;
typedef __attribute__((ext_vector_type(4))) float f32x4;

static __device__ __forceinline__ unsigned short f2bf(float f) {
    unsigned int u = __float_as_uint(f);
    unsigned int r = (u + 0x7fffu + ((u >> 16) & 1u)) >> 16;
    return (unsigned short)r;
}

static __device__ __forceinline__ void glds16(const void* g, void* l) {
    __builtin_amdgcn_global_load_lds(
        (const __attribute__((address_space(1))) unsigned int*)g,
        (__attribute__((address_space(3))) unsigned int*)l,
        16, 0, 0);
}

// Kernel 1: L2-normalize rows of x (N x 256 fp32) -> xn (bf16). Zero out[0].
__global__ __launch_bounds__(256) void normalize_kernel(
    const float* __restrict__ x, unsigned short* __restrict__ xn,
    float* __restrict__ out, int N) {
    const int wave = threadIdx.x >> 6;
    const int lane = threadIdx.x & 63;
    const int row  = blockIdx.x * 4 + wave;
    if (row >= N) return;

    if (blockIdx.x == 0 && threadIdx.x == 0) out[0] = 0.0f;

    const float4 v = ((const float4*)(x + (size_t)row * 256))[lane];
    float s = v.x * v.x + v.y * v.y + v.z * v.z + v.w * v.w;
    s += __shfl_xor(s, 1);
    s += __shfl_xor(s, 2);
    s += __shfl_xor(s, 4);
    s += __shfl_xor(s, 8);
    s += __shfl_xor(s, 16);
    s += __shfl_xor(s, 32);
    const float norm = fmaxf(sqrtf(s), 1e-12f);
    const float rinv = 1.0f / norm;

    ushort4 o;
    o.x = f2bf(v.x * rinv);
    o.y = f2bf(v.y * rinv);
    o.z = f2bf(v.z * rinv);
    o.w = f2bf(v.w * rinv);
    ((ushort4*)(xn + (size_t)row * 256))[lane] = o;
}

// Kernel 2: symmetric fused S = Xn*Xn^T on upper-triangle 256x256 tiles.
// 8 waves (2M x 4N), per-wave 128x64 output (acc = 128 AGPR). BK=64,
// double-buffered LDS 2 x (A 32KB + B 32KB) = 128 KB, 1 block/CU.
// Fat blocks: 64 MFMA per wave per barrier (vs 16 at 128^2) amortize the
// per-step barrier/latency tail 4x. Schedule: stage(t+1) before compute(t),
// one __syncthreads per K-tile (proven round-3 structure, scaled).
// LDS layout: [256][64] bf16 (128 B rows), 16B chunk c of row r stored at
// c ^ (r&7) -> ds_read_b128 is 2-way bank-aliased (free); glds sources are
// pre-swizzled per lane so the linear DMA destination yields this layout.
// Atomic-free epilogue (unique-writer slots):
//   row-partials of tile (bi,bj), wave (wm,wn) -> prowR[4*bj+wn], rows of bi
//   col-partials of tile (bi,bj), wave (wm,wn) -> prowC[2*bi+wm], rows of bj
// Coverage for row-block a: prowR slots [4a,128) (tiles (a,bj), bj>=a),
// prowC slots [0,2a) (tiles (bi,a), bi<a). Each cell written exactly once.
__global__ __launch_bounds__(512, 2) void gemm_exp_rowsum_kernel(
    const unsigned short* __restrict__ xn, float* __restrict__ prowR,
    float* __restrict__ prowC, int N) {
    const int D = 256;
    __shared__ unsigned short As[2][256 * 64];  // 2 x 32 KB
    __shared__ unsigned short Bs[2][256 * 64];  // 2 x 32 KB

    const int tid   = threadIdx.x;
    const int wave  = tid >> 6;     // 0..7
    const int lane  = tid & 63;
    const int waveM = wave >> 2;    // 0..1 (128-row half)
    const int waveN = wave & 3;     // 0..3 (64-col quarter)
    const int quad  = lane >> 4;
    const int l16   = lane & 15;

    // decode upper-triangle tile pair (bi <= bj), B = 32 tiles per dim
    const int B = N >> 8;
    const int t = blockIdx.x;
    int bi = (int)((2.0 * B + 1.0 -
                    sqrt((2.0 * B + 1.0) * (2.0 * B + 1.0) - 8.0 * (double)t)) * 0.5);
    while (bi > 0 && t < bi * B - (bi * (bi - 1)) / 2) --bi;
    while (t >= (bi + 1) * B - ((bi + 1) * bi) / 2) ++bi;
    const int bj = bi + (t - (bi * B - (bi * (bi - 1)) / 2));
    const bool diag = (bi == bj);

    const int iBase = bi * 256;
    const int jBase = bj * 256;

    f32x4 acc[8][4];
    #pragma unroll
    for (int mt = 0; mt < 8; ++mt)
        #pragma unroll
        for (int nt = 0; nt < 4; ++nt)
            acc[mt][nt] = (f32x4){0.f, 0.f, 0.f, 0.f};

    // staging: wave w owns rows [w*32, w*32+32). Each glds16 moves 8 rows x
    // 128 B (1 KB): lane l -> row +(l>>3), chunk l&7; source chunk pre-swizzled
    // (l&7) ^ ((l>>3)&7) so stored[r][c] = global[r][c ^ (r&7)].
    const int lrow8 = lane >> 3;
    const int csrc  = (lane & 7) ^ ((lane >> 3) & 7);

    auto stage = [&](int buf, int k0) {
        #pragma unroll
        for (int it = 0; it < 4; ++it) {
            const int r = wave * 32 + it * 8 + lrow8;   // 0..255
            glds16(xn + (size_t)(iBase + r) * D + k0 + csrc * 8,
                   &As[buf][(wave * 32 + it * 8) * 64]);
            glds16(xn + (size_t)(jBase + r) * D + k0 + csrc * 8,
                   &Bs[buf][(wave * 32 + it * 8) * 64]);
        }
    };

    // ds_read: logical chunk cl = ks*4 + quad of row r -> stored cl ^ (r&7);
    // r&7 == l16&7 for all fragment rows (row bases are multiples of 16).
    const int swz0 = ((0 * 4 + quad) ^ (l16 & 7)) * 8;
    const int swz1 = ((1 * 4 + quad) ^ (l16 & 7)) * 8;
    const int rowA = waveM * 128 + l16;   // + mt*16
    const int rowB = waveN * 64 + l16;    // + nt*16

    stage(0, 0);
    __syncthreads();

    #pragma unroll
    for (int kt = 0; kt < 4; ++kt) {
        const int cb = kt & 1;
        if (kt < 3) stage(cb ^ 1, (kt + 1) * 64);

        const unsigned short* Ap = &As[cb][0];
        const unsigned short* Bp = &Bs[cb][0];

        #pragma unroll
        for (int ks = 0; ks < 2; ++ks) {
            const int swz = ks ? swz1 : swz0;
            bf16x8 a[8], b[4];
            #pragma unroll
            for (int mt = 0; mt < 8; ++mt)
                a[mt] = *(const bf16x8*)(Ap + (rowA + mt * 16) * 64 + swz);
            #pragma unroll
            for (int nt = 0; nt < 4; ++nt)
                b[nt] = *(const bf16x8*)(Bp + (rowB + nt * 16) * 64 + swz);

            __builtin_amdgcn_s_setprio(1);
            #pragma unroll
            for (int mt = 0; mt < 8; ++mt)
                #pragma unroll
                for (int nt = 0; nt < 4; ++nt)
                    acc[mt][nt] = __builtin_amdgcn_mfma_f32_16x16x32_bf16(
                        a[mt], b[nt], acc[mt][nt], 0, 0, 0);
            __builtin_amdgcn_s_setprio(0);
        }

        if (kt < 3) __syncthreads();
    }

    // Epilogue. C/D layout: col = l16, row = quad*4 + reg  [m89/m91]
    float rsum[8][4];
    float csum[4] = {0.f, 0.f, 0.f, 0.f};
    #pragma unroll
    for (int mt = 0; mt < 8; ++mt)
        #pragma unroll
        for (int r = 0; r < 4; ++r) rsum[mt][r] = 0.f;

    #pragma unroll
    for (int mt = 0; mt < 8; ++mt) {
        const int gi0 = iBase + waveM * 128 + mt * 16 + quad * 4;
        #pragma unroll
        for (int nt = 0; nt < 4; ++nt) {
            const int gj = jBase + waveN * 64 + nt * 16 + l16;
            #pragma unroll
            for (int r = 0; r < 4; ++r) {
                float e = __builtin_amdgcn_exp2f(acc[mt][nt][r] * TAU_INV_LOG2E);
                if (gi0 + r == gj) e = 0.0f;  // diagonal (diag tiles only)
                rsum[mt][r] += e;
                csum[nt] += e;
            }
        }
    }
    // row partials -> prowR slot 4*bj + waveN
    {
        float* slot = prowR + (size_t)(4 * bj + waveN) * N;
        #pragma unroll
        for (int mt = 0; mt < 8; ++mt) {
            const int gi0 = iBase + waveM * 128 + mt * 16 + quad * 4;
            #pragma unroll
            for (int r = 0; r < 4; ++r) {
                float s = rsum[mt][r];
                s += __shfl_xor(s, 1);
                s += __shfl_xor(s, 2);
                s += __shfl_xor(s, 4);
                s += __shfl_xor(s, 8);
                if (l16 == 0) slot[gi0 + r] = s;
            }
        }
    }
    // col partials (symmetry) -> prowC slot 2*bi + waveM, off-diag only
    if (!diag) {
        float* slot = prowC + (size_t)(2 * bi + waveM) * N;
        #pragma unroll
        for (int nt = 0; nt < 4; ++nt) {
            float s = csum[nt];
            s += __shfl_xor(s, 16);
            s += __shfl_xor(s, 32);
            if (quad == 0)
                slot[jBase + waveN * 64 + nt * 16 + l16] = s;
        }
    }
}

// Kernel 3: per row-block a (256 rows), rowsum_i = sum of valid slots;
// loss += log(rowsum/(N-1)+eps)/N. Grid = 32 blocks x 256 threads.
__global__ __launch_bounds__(256) void finalize_kernel(
    const float* __restrict__ prowR, const float* __restrict__ prowC,
    float* __restrict__ out, int N) {
    __shared__ float red[4];
    const int a = blockIdx.x;           // row-block 0..31
    const int i = a * 256 + threadIdx.x;
    float s = 0.f;
    for (int p = 4 * a; p < 128; ++p) s += prowR[(size_t)p * N + i];
    for (int p = 0; p < 2 * a; ++p)   s += prowC[(size_t)p * N + i];
    float acc = logf(fmaf(s, 1.0f / (float)(N - 1), EPS));
    acc += __shfl_xor(acc, 1);
    acc += __shfl_xor(acc, 2);
    acc += __shfl_xor(acc, 4);
    acc += __shfl_xor(acc, 8);
    acc += __shfl_xor(acc, 16);
    acc += __shfl_xor(acc, 32);
    const int wave = threadIdx.x >> 6;
    const int lane = threadIdx.x & 63;
    if (lane == 0) red[wave] = acc;
    __syncthreads();
    if (threadIdx.x == 0)
        atomicAdd(out, (red[0] + red[1] + red[2] + red[3]) / (float)N);
}

extern "C" void kernel_launch(void* const* d_in, const int* in_sizes, int n_in,
                              void* d_out, int out_size, void* d_ws, size_t ws_size,
                              hipStream_t stream) {
    const float* x = (const float*)d_in[0];
    const int D = 256;
    const int N = in_sizes[0] / D;  // 8192
    const int B = N / 256;          // 32

    unsigned short* xn = (unsigned short*)d_ws;                 // 4 MB
    float* prowR = (float*)((char*)d_ws + (size_t)N * D * 2);   // 128 x N = 4 MB
    float* prowC = prowR + (size_t)128 * N;                     // 64 x N = 2 MB
    float* out = (float*)d_out;

    normalize_kernel<<<(N + 3) / 4, 256, 0, stream>>>(x, xn, out, N);

    const int T = B * (B + 1) / 2;  // 528 upper-triangle tiles
    gemm_exp_rowsum_kernel<<<T, 512, 0, stream>>>(xn, prowR, prowC, N);

    finalize_kernel<<<B, 256, 0, stream>>>(prowR, prowC, out, N);
}